// Round 7
// baseline (512.060 us; speedup 1.0000x reference)
//
#include <hip/hip_runtime.h>
#include <hip/hip_bf16.h>

// ---------------------------------------------------------------------------
// QLSTM: seq=256, batch=512, input=256, H=n_qubits=8.
// FUSED producer/consumer kernel:
//   blocks 32..511 (1920 wave-slots): MFMA gemm, 16-row chunks, iter-major
//     sweep; per-chunk release-store flags[c]=MAGIC (agent scope => wb L2).
//   blocks 0..31 (128 scan waves): R6-verified scan math; Z + flags read via
//     relaxed agent-scope (cache-bypassing) atomic loads, gated per 8-slice
//     group with flags prefetched one group ahead.
// flags zeroed by a tiny kernel first (poison-safe). No barriers => no
// deadlock; adversarial scheduling degenerates to serialization (correct).
// ---------------------------------------------------------------------------

#define SEQ   256
#define BATCH 512
#define DIN   256
#define NROWS (SEQ * BATCH)      // 131072
#define DCOMB 264                // 256 + 8
#define ZBYTES (NROWS * 32 * 4)  // 16.8 MB

#define NSCAN  32
#define NBLK   512
#define WSLOTS ((NBLK - NSCAN) * 4)   // 1920 producer wave-slots
#define NCHUNK (NROWS / 16)           // 8192 chunks (16 rows each)
#define MAGIC  0x13579BDFu

typedef __attribute__((ext_vector_type(8))) short short8;
typedef __attribute__((ext_vector_type(4))) float f32x4;
typedef __attribute__((ext_vector_type(2))) float f32x2;

__device__ __forceinline__ short f2bf(float f) {
    union { __hip_bfloat16 h; short s; } u;
    u.h = __float2bfloat16(f);
    return u.s;
}
__device__ __forceinline__ float bf2f(short s) {
    union { short s; __hip_bfloat16 h; } u;
    u.s = s;
    return __bfloat162float(u.h);
}
__device__ __forceinline__ short8 pack8(float4 a, float4 b) {
    union { short8 s8; int i[4]; } u;
    union { __hip_bfloat162 h; int i; } v;
    v.h = __float22bfloat162_rn(make_float2(a.x, a.y)); u.i[0] = v.i;
    v.h = __float22bfloat162_rn(make_float2(a.z, a.w)); u.i[1] = v.i;
    v.h = __float22bfloat162_rn(make_float2(b.x, b.y)); u.i[2] = v.i;
    v.h = __float22bfloat162_rn(make_float2(b.z, b.w)); u.i[3] = v.i;
    return u.s8;
}

// DPP conventions (verified R1..R6 passing):
//   row_shr:d -> dst[i]=src[i-d] (invalid -> old); row_ror:s -> dst[i]=src[(i-s)%16]
#define DPP_ROR(V, S) \
    __int_as_float(__builtin_amdgcn_update_dpp(__float_as_int(V), __float_as_int(V), 0x120 | (S), 0xF, 0xF, false))
#define SWAP8(V) \
    __int_as_float(__builtin_amdgcn_update_dpp(__float_as_int(V), __float_as_int(V), 0x128, 0xF, 0xF, false))
#define DPP_REPL8(V) \
    __int_as_float(__builtin_amdgcn_update_dpp(__float_as_int(V), __float_as_int(V), 0x118, 0xF, 0xF, false))
#define PSTG(A, D, PM) { \
    float s0_ = __int_as_float(__builtin_amdgcn_update_dpp(one_i, __float_as_int(A.x), 0x110 | (D), 0xF, 0xF, false)); \
    float s1_ = __int_as_float(__builtin_amdgcn_update_dpp(one_i, __float_as_int(A.y), 0x110 | (D), 0xF, 0xF, false)); \
    A *= (f32x2){ (PM) ? s0_ : 1.0f, (PM) ? s1_ : 1.0f }; }

#define PF 8   // Z ring depth == group size

__global__ __launch_bounds__(256) void flags_zero(unsigned* __restrict__ flags) {
    flags[blockIdx.x * 256 + threadIdx.x] = 0u;
}

__global__ __launch_bounds__(256, 2) void qlstm_fused(
    const float* __restrict__ X,
    const float* __restrict__ Wf, const float* __restrict__ Wi,
    const float* __restrict__ Wu, const float* __restrict__ Wo,
    const float* __restrict__ bfv, const float* __restrict__ biv,
    const float* __restrict__ buv, const float* __restrict__ bov,
    const float* __restrict__ pf, const float* __restrict__ pi_,
    const float* __restrict__ pu, const float* __restrict__ po,
    float* __restrict__ Z, unsigned* __restrict__ flags,
    float* __restrict__ out)
{
    const int wid = threadIdx.x >> 6;
    const int l   = threadIdx.x & 63;

    if (blockIdx.x >= NSCAN) {
        // ======================= PRODUCER (gemm) ==========================
        const int lm = l & 15, lk = l >> 4;
        const float* Wg[4] = {Wf, Wi, Wu, Wo};
        const float* Bg[4] = {bfv, biv, buv, bov};

        short8 Bhi[2][8], Blo[2][8];
        float bias[2];
        #pragma unroll
        for (int nt = 0; nt < 2; ++nt) {
            const int c = nt * 16 + lm;              // col = kq*4 + g
            const float* wrow = Wg[c & 3] + (c >> 2) * DCOMB;
            bias[nt] = Bg[c & 3][c >> 2];
            #pragma unroll
            for (int ks = 0; ks < 8; ++ks) {
                const float* p = wrow + ks * 32 + lk * 8;
                const float4 w0 = *(const float4*)p;
                const float4 w1 = *(const float4*)(p + 4);
                const float wv[8] = {w0.x, w0.y, w0.z, w0.w, w1.x, w1.y, w1.z, w1.w};
                #pragma unroll
                for (int j = 0; j < 8; ++j) {
                    const short hi = f2bf(wv[j]);
                    Bhi[nt][ks][j] = hi;
                    Blo[nt][ks][j] = f2bf(wv[j] - bf2f(hi));
                }
            }
        }

        const int wslot = (blockIdx.x - NSCAN) * 4 + wid;
        #pragma unroll 1
        for (int c = wslot; c < NCHUNK; c += WSLOTS) {   // iter-major sweep
            const int row0 = c * 16;
            const float* xbase = X + (long)(row0 + lm) * DIN + lk * 8;

            float4 xv[16];
            #pragma unroll
            for (int i = 0; i < 16; ++i)
                xv[i] = *(const float4*)(xbase + (i >> 1) * 32 + (i & 1) * 4);

            f32x4 acc0 = (f32x4){bias[0], bias[0], bias[0], bias[0]};
            f32x4 acc1 = (f32x4){bias[1], bias[1], bias[1], bias[1]};
            #pragma unroll
            for (int ks = 0; ks < 8; ++ks) {
                const short8 a = pack8(xv[2 * ks], xv[2 * ks + 1]);
                acc0 = __builtin_amdgcn_mfma_f32_16x16x32_bf16(a, Bhi[0][ks], acc0, 0, 0, 0);
                acc0 = __builtin_amdgcn_mfma_f32_16x16x32_bf16(a, Blo[0][ks], acc0, 0, 0, 0);
                acc1 = __builtin_amdgcn_mfma_f32_16x16x32_bf16(a, Bhi[1][ks], acc1, 0, 0, 0);
                acc1 = __builtin_amdgcn_mfma_f32_16x16x32_bf16(a, Blo[1][ks], acc1, 0, 0, 0);
            }

            #pragma unroll
            for (int r = 0; r < 4; ++r) {
                Z[(long)(row0 + lk * 4 + r) * 32 + lm]      = acc0[r];
                Z[(long)(row0 + lk * 4 + r) * 32 + 16 + lm] = acc1[r];
            }

            // release: waitcnt + L2 writeback + flag store at coherent point
            if (l == 0)
                __hip_atomic_store(&flags[c], MAGIC, __ATOMIC_RELEASE,
                                   __HIP_MEMORY_SCOPE_AGENT);
        }
        return;
    }

    // ========================== SCANNER ==================================
    const int sid  = blockIdx.x * 256 + threadIdx.x;  // 0..8191
    const int q    = sid & 15;
    const int kq   = q & 7;
    const int hi   = q >> 3;                          // 0:(f,i)  1:(u,o)
    const int b    = sid >> 4;
    const int oidx = b * 8 + kq;
    const int woff = kq * DCOMB + DIN;

    const float* WgA = hi ? Wu : Wf;
    const float* WgB = hi ? Wo : Wi;
    f32x2 wp[8];
    #pragma unroll
    for (int s = 0; s < 8; ++s) {
        const int j = (kq - s) & 7;
        wp[s] = (f32x2){WgA[woff + j], WgB[woff + j]};
    }
    const f32x2 cth = (f32x2){__cosf((hi ? pu : pf)[kq]),
                              __cosf((hi ? po : pi_)[kq])};

    const float SK1 = 0.25f, SK2 = -0.0208333333f, SK3 = 0.0020833333f,
                SK4 = -0.00021082f;
    const f32x2 k0 = (f32x2){hi ? 0.0f : 0.5f, 0.5f};
    const f32x2 k1 = (f32x2){hi ? 0.9999016f : SK1, SK1};
    const f32x2 k2 = (f32x2){hi ? -0.3310485f : SK2, SK2};
    const f32x2 k3 = (f32x2){hi ? 0.1204423f : SK3, SK3};
    const f32x2 k4 = (f32x2){hi ? -0.0277012f : SK4, SK4};

    const bool pm1 = kq >= 1, pm2 = kq >= 2, pm4 = kq >= 4;
    const int one_i = __float_as_int(1.0f);

    float hx = 0.0f, cx = 0.0f;
    const int zoff = b * 16 + kq * 2 + hi;            // float2 idx in a t-slice
    float* __restrict__ outp = out + oidx;

    // cache-bypassing (agent-scope) loads: read the coherent point
    #define LDF(S, J) __hip_atomic_load( \
        flags + ((S) * 32) + (l * 4 + (J)), __ATOMIC_RELAXED, __HIP_MEMORY_SCOPE_AGENT)
    #define ZLD(SL) ({ \
        union { unsigned long long u; float2 f; } cv_; \
        cv_.u = __hip_atomic_load((const unsigned long long*)Z + \
                 (((long)(SL)) << 13) + zoff, __ATOMIC_RELAXED, \
                 __HIP_MEMORY_SCOPE_AGENT); \
        cv_.f; })

    // blocking wait for slices s0..s0+7 (capped spin: no hang, ever)
    #define SPIN8(S0) { \
        for (int sp_ = 0; sp_ < (1 << 17); ++sp_) { \
            unsigned a_ = LDF(S0, 0), b_ = LDF(S0, 1); \
            unsigned c_ = LDF(S0, 2), d_ = LDF(S0, 3); \
            if (__all((a_ == MAGIC) & (b_ == MAGIC) & (c_ == MAGIC) & (d_ == MAGIC))) break; \
            __builtin_amdgcn_s_sleep(8); \
        } }

    SPIN8(0)                                          // slices 0..7 ready
    float2 ring[PF];
    #pragma unroll
    for (int i = 0; i < PF; ++i) ring[i] = ZLD(i);
    unsigned f0 = LDF(PF, 0), f1 = LDF(PF, 1);        // prefetch flags 8..15
    unsigned f2 = LDF(PF, 2), f3 = LDF(PF, 3);

    #pragma unroll 1
    for (int t0 = 0; t0 < SEQ; t0 += PF) {
        if (t0 + PF < SEQ) {
            if (!__all((f0 == MAGIC) & (f1 == MAGIC) & (f2 == MAGIC) & (f3 == MAGIC)))
                SPIN8(t0 + PF)
            if (t0 + 2 * PF < SEQ) {                  // prefetch next group
                f0 = LDF(t0 + 2 * PF, 0); f1 = LDF(t0 + 2 * PF, 1);
                f2 = LDF(t0 + 2 * PF, 2); f3 = LDF(t0 + 2 * PF, 3);
            }
        }
        #pragma unroll
        for (int u = 0; u < PF; ++u) {
            const int t = t0 + u;
            const float2 z2 = ring[u];
            int tn = t + PF; if (tn > SEQ - 1) tn = SEQ - 1;
            ring[u] = ZLD(tn);                        // gated by group check

            const float h0 = hx;
            const float h1 = DPP_ROR(hx, 1), h2 = DPP_ROR(hx, 2);
            const float h3 = DPP_ROR(hx, 3), h4 = DPP_ROR(hx, 4);
            const float h5 = DPP_ROR(hx, 5), h6 = DPP_ROR(hx, 6);
            const float h7 = DPP_ROR(hx, 7);

            f32x2 ca = (f32x2){h0, h0} * wp[0] + (f32x2){h1, h1} * wp[1];
            f32x2 cb = (f32x2){h4, h4} * wp[4] + (f32x2){h5, h5} * wp[5];
            ca += (f32x2){h2, h2} * wp[2];
            cb += (f32x2){h6, h6} * wp[6];
            ca += (f32x2){h3, h3} * wp[3];
            cb += (f32x2){h7, h7} * wp[7];
            const f32x2 p = ((f32x2){z2.x, z2.y} + ca) + cb;

            f32x2 A = (f32x2){__cosf(p.x), __cosf(p.y)} * cth;
            PSTG(A, 1, pm1) PSTG(A, 2, pm2) PSTG(A, 4, pm4)

            const f32x2 t2 = A * A;
            f32x2 r = k3 + t2 * k4;
            r = k2 + t2 * r;
            r = k1 + t2 * r;
            const f32x2 P = k0 + A * r;
            const float v1 = P.x;                     // low: fg   high: ug
            const float v2 = P.y;                     // low: ig   high: og

            const float swu = SWAP8(v1);
            cx = fmaf(v1, cx, v2 * swu);

            const float tq  = cx * cx;
            const float num = cx * fmaf(tq, fmaf(tq, 1.0f, 105.0f), 945.0f);
            const float den = fmaf(tq, fmaf(tq, 15.0f, 420.0f), 945.0f);
            const float tc  = num * __builtin_amdgcn_rcpf(den);

            const float stc = SWAP8(tc);
            const float hh  = v2 * stc;
            hx = SWAP8(hh);
            hx = DPP_REPL8(hx);

            outp[t << 12] = hx;
        }
    }
    if (q < 8) {
        out[NROWS * 8 + oidx]        = hx;            // final hx (512,8)
        out[NROWS * 8 + 4096 + oidx] = cx;            // final cx (512,8)
    }
}

// ---------------------------------------------------------------------------
extern "C" void kernel_launch(void* const* d_in, const int* in_sizes, int n_in,
                              void* d_out, int out_size, void* d_ws, size_t ws_size,
                              hipStream_t stream) {
    const float* X   = (const float*)d_in[0];
    const float* Wf  = (const float*)d_in[1];
    const float* bfv = (const float*)d_in[2];
    const float* Wi  = (const float*)d_in[3];
    const float* biv = (const float*)d_in[4];
    const float* Wu  = (const float*)d_in[5];
    const float* buv = (const float*)d_in[6];
    const float* Wo  = (const float*)d_in[7];
    const float* bov = (const float*)d_in[8];
    const float* pf  = (const float*)d_in[9];
    const float* pi_ = (const float*)d_in[10];
    const float* pu  = (const float*)d_in[11];
    const float* po  = (const float*)d_in[12];
    float* out = (float*)d_out;

    char* ws = (char*)d_ws;
    float*    Z     = (float*)ws;                 // 16.8 MB
    unsigned* flags = (unsigned*)(ws + ZBYTES);   // 8192 * 4 B

    flags_zero<<<NCHUNK / 256, 256, 0, stream>>>(flags);
    qlstm_fused<<<NBLK, 256, 0, stream>>>(
        X, Wf, Wi, Wu, Wo, bfv, biv, buv, bov, pf, pi_, pu, po, Z, flags, out);
}